// Round 6
// baseline (63.898 us; speedup 1.0000x reference)
//
#include <hip/hip_runtime.h>

// TropConv2D: out[b,ho,wo,f] = max_k(patch_k + w[k,f]) - min_k(patch_k + w[k,f])
// x: (8,32,32,32) f32 NHWC, w: (288,64) f32 (72 KB), out: (8,30,30,64) f32
// k = (i*3 + j)*32 + c   (TF extract_patches ordering)
//
// v6: get OFF the LDS pipe. v2/v5 benched equal with identical 576
//   ds_read_b128/block main loops (~11 us/CU of LDS-pipe serialization) ->
//   LDS-pipe-bound diagnosis. Patch reads are wave-uniform, so:
//   - wave = readfirstlane(tid>>6) makes patch addresses provably uniform ->
//     compiler selects s_load_dwordx4 (SMEM/K$), zero LDS + zero VMEM pipe.
//   - No xs staging, no staging barrier. LDS only for the 8-way cross-wave
//     combine (24 b32/wave, negligible).
//   - Weights stay lane-coalesced VMEM (36 x 256 B per wave, L2-hot).
//   - px processed in two halves of 4 with p[6] col window so the
//     VGPR-fallback live set stays <=~60 regs (anti-spill hedge; v3/v4
//     lesson: allocator targets 64 VGPRs and spills rather than lowering
//     occupancy).
//   grid = 960, block = 512 (8 waves; wave = 4-channel slice).
//   Max/min associative -> channel-split partials exact (absmax 0).

#define C_IN 32
#define NF 64
#define H_OUT 30
#define W_OUT 30
#define W_IN 32

static __device__ __forceinline__ float max3f(float a, float b, float c) {
    return fmaxf(fmaxf(a, b), c);
}
static __device__ __forceinline__ float min3f(float a, float b, float c) {
    return fminf(fminf(a, b), c);
}

__global__ __launch_bounds__(512) void tropconv_kernel(
    const float* __restrict__ x,
    const float* __restrict__ w,
    float* __restrict__ out) {
    const int bx = blockIdx.x;            // 0..959
    const int q = bx & 3;                 // row quarter
    const int bho = bx >> 2;              // b*30 + ho
    const int b = bho / H_OUT;
    const int ho = bho - b * H_OUT;
    const int tid = threadIdx.x;
    const int lane = tid & 63;            // filter index
    const int wave = __builtin_amdgcn_readfirstlane(tid >> 6);  // uniform 0..7

    const int col0 = q * 8;
    const int npx = (q == 3) ? 6 : 8;
    const int cmax = (q == 3) ? 7 : 9;    // clamp patch cols in-bounds (q=3)

    __shared__ float pmx[8][8][NF];       // 16 KB partial max
    __shared__ float pmn[8][8][NF];       // 16 KB partial min

    float mx[8], mn[8];
    #pragma unroll
    for (int t = 0; t < 8; ++t) { mx[t] = -INFINITY; mn[t] = INFINITY; }

    // weights for this wave's 4-channel slice: w[(k)*64 + lane], k = ij*32 + wave*4 + c
    const float* __restrict__ wbase = w + (size_t)(wave * 4) * NF + lane;

    #pragma unroll
    for (int i = 0; i < 3; ++i) {
        // 12 weights for window row i (lane-coalesced 256 B loads, L2-hot)
        float wr[12];
        #pragma unroll
        for (int j = 0; j < 3; ++j)
            #pragma unroll
            for (int c = 0; c < 4; ++c)
                wr[j * 4 + c] = wbase[((i * 3 + j) * C_IN + c) * NF];

        // uniform base of input row ho+i at col0, this wave's channel slice
        const float4* __restrict__ row4 = (const float4*)(
            x + ((size_t)((b * 32 + ho + i) * W_IN + col0)) * C_IN) + wave;

        #pragma unroll
        for (int half = 0; half < 2; ++half) {
            // 6 patch cols, wave-uniform addresses -> scalar (SMEM) loads
            float4 p[6];
            #pragma unroll
            for (int t = 0; t < 6; ++t) {
                int col = half * 4 + t;
                if (col > cmax) col = cmax;   // q=3: stay in-bounds, junk discarded
                p[t] = row4[col * 8];
            }
            #pragma unroll
            for (int px = 0; px < 4; ++px) {
                const int g = half * 4 + px;
                float s0  = p[px].x     + wr[0],  s1  = p[px].y     + wr[1];
                float s2  = p[px].z     + wr[2],  s3  = p[px].w     + wr[3];
                float s4  = p[px + 1].x + wr[4],  s5  = p[px + 1].y + wr[5];
                float s6  = p[px + 1].z + wr[6],  s7  = p[px + 1].w + wr[7];
                float s8  = p[px + 2].x + wr[8],  s9  = p[px + 2].y + wr[9];
                float s10 = p[px + 2].z + wr[10], s11 = p[px + 2].w + wr[11];
                mx[g] = max3f(max3f(max3f(s0, s1, s2), max3f(s3, s4, s5),
                                    max3f(s6, s7, s8)),
                              max3f(s9, s10, s11), mx[g]);
                mn[g] = min3f(min3f(min3f(s0, s1, s2), min3f(s3, s4, s5),
                                    min3f(s6, s7, s8)),
                              min3f(s9, s10, s11), mn[g]);
            }
        }
    }

    #pragma unroll
    for (int t = 0; t < 8; ++t) {
        pmx[wave][t][lane] = mx[t];
        pmn[wave][t][lane] = mn[t];
    }
    __syncthreads();

    // ---- Cross-wave combine (exact: max/min associative) ----
    const int nout = npx * NF;            // 512 or 384
    if (tid < nout) {
        const int px = tid >> 6;
        const int f = tid & 63;
        float a = fmaxf(fmaxf(fmaxf(pmx[0][px][f], pmx[1][px][f]),
                              fmaxf(pmx[2][px][f], pmx[3][px][f])),
                        fmaxf(fmaxf(pmx[4][px][f], pmx[5][px][f]),
                              fmaxf(pmx[6][px][f], pmx[7][px][f])));
        float m = fminf(fminf(fminf(pmn[0][px][f], pmn[1][px][f]),
                              fminf(pmn[2][px][f], pmn[3][px][f])),
                        fminf(fminf(pmn[4][px][f], pmn[5][px][f]),
                              fminf(pmn[6][px][f], pmn[7][px][f])));
        out[((size_t)bho * W_OUT + (col0 + px)) * NF + f] = a - m;
    }
}

extern "C" void kernel_launch(void* const* d_in, const int* in_sizes, int n_in,
                              void* d_out, int out_size, void* d_ws, size_t ws_size,
                              hipStream_t stream) {
    const float* x = (const float*)d_in[0];   // 8*32*32*32
    const float* w = (const float*)d_in[1];   // 288*64
    float* out = (float*)d_out;               // 8*30*30*64

    dim3 grid(8 * H_OUT * 4);                 // 960 blocks
    dim3 block(512);
    tropconv_kernel<<<grid, block, 0, stream>>>(x, w, out);
}